// Round 5
// baseline (62.545 us; speedup 1.0000x reference)
//
#include <hip/hip_runtime.h>

#define NUM_INPUT   256
#define NUM_OUTPUT  64
#define MAX_DEPTH   10
#define N_INTERNAL  1023
#define STAGED_NODES 63          // tree levels 0..5 staged in LDS
#define STAGED_DEPTH 6
#define ELEMS_PER_WAVE 4         // 16 lanes per element
#define WAVES_PER_BLOCK 16
#define THREADS (WAVES_PER_BLOCK * 64)   // 1024
#define BLOCKS 512                        // 2 blocks/CU resident for whole kernel
#define ROUNDS 4                          // 131072 / (512*16*4)

// Sum-reduce across each 16-lane row using DPP row_ror (VALU pipe, no DS ops).
__device__ __forceinline__ float group16_reduce(float acc) {
    int t;
    t = __builtin_amdgcn_update_dpp(0, __float_as_int(acc), 0x121, 0xf, 0xf, true); // row_ror:1
    acc += __int_as_float(t);
    t = __builtin_amdgcn_update_dpp(0, __float_as_int(acc), 0x122, 0xf, 0xf, true); // row_ror:2
    acc += __int_as_float(t);
    t = __builtin_amdgcn_update_dpp(0, __float_as_int(acc), 0x124, 0xf, 0xf, true); // row_ror:4
    acc += __int_as_float(t);
    t = __builtin_amdgcn_update_dpp(0, __float_as_int(acc), 0x128, 0xf, 0xf, true); // row_ror:8
    acc += __int_as_float(t);
    return acc;
}

// One depth step. Dot = 4 parallel accumulators (shorter dep chain); the
// branch uses z>=0 (== sigmoid(z)>=0.5) so expf/rcp are OFF the critical
// path — only `mult` needs them and it dangles.
#define DEPTH_STEP(WROW_PTR)                                               \
    {                                                                      \
        const float4* wrow = (WROW_PTR);                                   \
        float a_i = lds_a[idx];                                            \
        float b_i = lds_b[idx];                                            \
        float4 w0 = wrow[0 * 16 + s];                                      \
        float4 w1 = wrow[1 * 16 + s];                                      \
        float4 w2 = wrow[2 * 16 + s];                                      \
        float4 w3 = wrow[3 * 16 + s];                                      \
        float acc0 = xv0.x * w0.x, acc1 = xv1.x * w1.x;                    \
        float acc2 = xv2.x * w2.x, acc3 = xv3.x * w3.x;                    \
        acc0 = fmaf(xv0.y, w0.y, acc0); acc1 = fmaf(xv1.y, w1.y, acc1);    \
        acc2 = fmaf(xv2.y, w2.y, acc2); acc3 = fmaf(xv3.y, w3.y, acc3);    \
        acc0 = fmaf(xv0.z, w0.z, acc0); acc1 = fmaf(xv1.z, w1.z, acc1);    \
        acc2 = fmaf(xv2.z, w2.z, acc2); acc3 = fmaf(xv3.z, w3.z, acc3);    \
        acc0 = fmaf(xv0.w, w0.w, acc0); acc1 = fmaf(xv1.w, w1.w, acc1);    \
        acc2 = fmaf(xv2.w, w2.w, acc2); acc3 = fmaf(xv3.w, w3.w, acc3);    \
        float acc = (acc0 + acc1) + (acc2 + acc3);                         \
        acc = group16_reduce(acc);                                         \
        float z = a_i * (acc + b_i);                                       \
        bool right = (z >= 0.0f);                                          \
        idx = 2 * idx + 1 + (right ? 1 : 0);                               \
        float val = 1.0f / (1.0f + __expf(-z));                            \
        mult *= right ? val : (1.0f - val);                                \
    }

__global__ __launch_bounds__(THREADS, 8) void ogtree_kernel(
    const float* __restrict__ x,
    const float* __restrict__ W,
    const float* __restrict__ b,
    const float* __restrict__ alpha,
    const float* __restrict__ leaves,
    float* __restrict__ out)
{
    __shared__ float lds_w[STAGED_NODES * NUM_INPUT];  // 63 KB
    __shared__ float lds_b[N_INTERNAL];                // 4 KB
    __shared__ float lds_a[N_INTERNAL];                // 4 KB

    const int tid = threadIdx.x;

    // ---- stage W levels 0..5 (rows 0..62) + all b/alpha — once per block ----
    {
        const float4* Wv = reinterpret_cast<const float4*>(W);
        float4* lw4 = reinterpret_cast<float4*>(lds_w);
        #pragma unroll
        for (int i = tid; i < STAGED_NODES * NUM_INPUT / 4; i += THREADS)
            lw4[i] = Wv[i];
        for (int i = tid; i < N_INTERNAL; i += THREADS) {
            lds_b[i] = b[i];
            lds_a[i] = alpha[i];
        }
    }
    __syncthreads();

    const int lane = tid & 63;
    const int wid  = tid >> 6;
    const int g    = lane >> 4;   // element slot within wave (0..3)
    const int s    = lane & 15;   // sub-lane within element group
    const int wave_base = blockIdx.x * (WAVES_PER_BLOCK * ELEMS_PER_WAVE * ROUNDS)
                        + wid * (ELEMS_PER_WAVE * ROUNDS);

    #pragma unroll 1   // keep rounds as a loop: small code, waves drift -> pipe overlap
    for (int r = 0; r < ROUNDS; ++r) {
        const int elem = wave_base + r * ELEMS_PER_WAVE + g;

        const float4* xrow = reinterpret_cast<const float4*>(x + (size_t)elem * NUM_INPUT);
        float4 xv0 = xrow[0 * 16 + s];
        float4 xv1 = xrow[1 * 16 + s];
        float4 xv2 = xrow[2 * 16 + s];
        float4 xv3 = xrow[3 * 16 + s];

        int   idx  = 0;
        float mult = 1.0f;

        // depths 0..5: W from LDS
        #pragma unroll
        for (int d = 0; d < STAGED_DEPTH; ++d)
            DEPTH_STEP(reinterpret_cast<const float4*>(lds_w + idx * NUM_INPUT));

        // depths 6..9: W gathered from global (L2-resident, 1 MB total)
        #pragma unroll
        for (int d = STAGED_DEPTH; d < MAX_DEPTH; ++d)
            DEPTH_STEP(reinterpret_cast<const float4*>(W + (size_t)idx * NUM_INPUT));

        // epilogue: out[elem] = mult * leaves[idx - 1023]
        const int leaf = idx - N_INTERNAL;
        const float4 lv = reinterpret_cast<const float4*>(
            leaves + (size_t)leaf * NUM_OUTPUT)[s];
        float4 o;
        o.x = mult * lv.x;
        o.y = mult * lv.y;
        o.z = mult * lv.z;
        o.w = mult * lv.w;
        reinterpret_cast<float4*>(out + (size_t)elem * NUM_OUTPUT)[s] = o;
    }
}

extern "C" void kernel_launch(void* const* d_in, const int* in_sizes, int n_in,
                              void* d_out, int out_size, void* d_ws, size_t ws_size,
                              hipStream_t stream) {
    const float* x      = (const float*)d_in[0];
    const float* W      = (const float*)d_in[1];
    const float* b      = (const float*)d_in[2];
    const float* alpha  = (const float*)d_in[3];
    const float* leaves = (const float*)d_in[4];
    float* out = (float*)d_out;

    ogtree_kernel<<<BLOCKS, THREADS, 0, stream>>>(x, W, b, alpha, leaves, out);
}

// Round 6
// 58.331 us; speedup vs baseline: 1.0722x; 1.0722x over previous
//
#include <hip/hip_runtime.h>

#define NUM_INPUT   256
#define NUM_OUTPUT  64
#define MAX_DEPTH   10
#define N_INTERNAL  1023
#define STAGED_NODES 63          // tree levels 0..5 staged in LDS
#define STAGED_DEPTH 6
#define WAVES_PER_BLOCK 16
#define THREADS (WAVES_PER_BLOCK * 64)   // 1024
#define BLOCKS 512
#define ROUNDS 4   // elements per 16-lane group: 512 blk * 16 waves * 4 grp * 4 = 131072

// Sum-reduce across each 16-lane row using DPP row_ror (VALU pipe, no DS ops).
__device__ __forceinline__ float group16_reduce(float acc) {
    int t;
    t = __builtin_amdgcn_update_dpp(0, __float_as_int(acc), 0x121, 0xf, 0xf, true); // row_ror:1
    acc += __int_as_float(t);
    t = __builtin_amdgcn_update_dpp(0, __float_as_int(acc), 0x122, 0xf, 0xf, true); // row_ror:2
    acc += __int_as_float(t);
    t = __builtin_amdgcn_update_dpp(0, __float_as_int(acc), 0x124, 0xf, 0xf, true); // row_ror:4
    acc += __int_as_float(t);
    t = __builtin_amdgcn_update_dpp(0, __float_as_int(acc), 0x128, 0xf, 0xf, true); // row_ror:8
    acc += __int_as_float(t);
    return acc;
}

// One depth step on chain (IDX, MULT) with x fragments X0..X3, weights from BASE.
// Decision via z>=0 (== sigmoid(z)>=0.5); expf/rcp dangle off the critical path.
#define DEPTH_STEP(BASE, IDX, MULT, X0, X1, X2, X3)                        \
    {                                                                      \
        const float4* wrow = reinterpret_cast<const float4*>(              \
            (BASE) + (size_t)(IDX) * NUM_INPUT);                           \
        float a_i = lds_a[IDX];                                            \
        float b_i = lds_b[IDX];                                            \
        float4 w0 = wrow[0 * 16 + s];                                      \
        float4 w1 = wrow[1 * 16 + s];                                      \
        float4 w2 = wrow[2 * 16 + s];                                      \
        float4 w3 = wrow[3 * 16 + s];                                      \
        float acc0 = X0.x * w0.x, acc1 = X1.x * w1.x;                      \
        float acc2 = X2.x * w2.x, acc3 = X3.x * w3.x;                      \
        acc0 = fmaf(X0.y, w0.y, acc0); acc1 = fmaf(X1.y, w1.y, acc1);      \
        acc2 = fmaf(X2.y, w2.y, acc2); acc3 = fmaf(X3.y, w3.y, acc3);      \
        acc0 = fmaf(X0.z, w0.z, acc0); acc1 = fmaf(X1.z, w1.z, acc1);      \
        acc2 = fmaf(X2.z, w2.z, acc2); acc3 = fmaf(X3.z, w3.z, acc3);      \
        acc0 = fmaf(X0.w, w0.w, acc0); acc1 = fmaf(X1.w, w1.w, acc1);      \
        acc2 = fmaf(X2.w, w2.w, acc2); acc3 = fmaf(X3.w, w3.w, acc3);      \
        float acc = (acc0 + acc1) + (acc2 + acc3);                         \
        acc = group16_reduce(acc);                                         \
        float z = a_i * (acc + b_i);                                       \
        bool right = (z >= 0.0f);                                          \
        IDX = 2 * (IDX) + 1 + (right ? 1 : 0);                             \
        float val = 1.0f / (1.0f + __expf(-z));                            \
        MULT *= right ? val : (1.0f - val);                                \
    }

#define STORE_OUT(ELEM, IDX, MULT)                                         \
    {                                                                      \
        const int leaf = (IDX) - N_INTERNAL;                               \
        const float4 lv = reinterpret_cast<const float4*>(                 \
            leaves + (size_t)leaf * NUM_OUTPUT)[s];                        \
        float4 o;                                                          \
        o.x = (MULT) * lv.x; o.y = (MULT) * lv.y;                          \
        o.z = (MULT) * lv.z; o.w = (MULT) * lv.w;                          \
        reinterpret_cast<float4*>(out + (size_t)(ELEM) * NUM_OUTPUT)[s] = o; \
    }

__global__ __launch_bounds__(THREADS) void ogtree_kernel(
    const float* __restrict__ x,
    const float* __restrict__ W,
    const float* __restrict__ b,
    const float* __restrict__ alpha,
    const float* __restrict__ leaves,
    float* __restrict__ out)
{
    __shared__ float lds_w[STAGED_NODES * NUM_INPUT];  // 63 KB
    __shared__ float lds_b[N_INTERNAL];                // 4 KB
    __shared__ float lds_a[N_INTERNAL];                // 4 KB

    const int tid = threadIdx.x;

    // ---- stage W levels 0..5 (rows 0..62) + all b/alpha ----
    {
        const float4* Wv = reinterpret_cast<const float4*>(W);
        float4* lw4 = reinterpret_cast<float4*>(lds_w);
        #pragma unroll
        for (int i = tid; i < STAGED_NODES * NUM_INPUT / 4; i += THREADS)
            lw4[i] = Wv[i];
        for (int i = tid; i < N_INTERNAL; i += THREADS) {
            lds_b[i] = b[i];
            lds_a[i] = alpha[i];
        }
    }
    __syncthreads();

    const int lane = tid & 63;
    const int wid  = tid >> 6;
    const int g    = lane >> 4;   // element slot within wave (0..3)
    const int s    = lane & 15;   // sub-lane within element group
    const int wbase = (blockIdx.x * WAVES_PER_BLOCK + wid) * (4 * ROUNDS);

    // ---- pipeline fill: element 0 through LDS depths 0..5 ----
    const float4* xr = reinterpret_cast<const float4*>(
        x + (size_t)(wbase + g) * NUM_INPUT);
    float4 xa0 = xr[0 * 16 + s], xa1 = xr[1 * 16 + s];
    float4 xa2 = xr[2 * 16 + s], xa3 = xr[3 * 16 + s];
    int idxA = 0; float multA = 1.0f;
    #pragma unroll
    for (int d = 0; d < STAGED_DEPTH; ++d)
        DEPTH_STEP(lds_w, idxA, multA, xa0, xa1, xa2, xa3);

    // ---- steady state: LDS-phase(elem r) overlapped with L2-phase(elem r-1) ----
    #pragma unroll 1
    for (int r = 1; r < ROUNDS; ++r) {
        // rotate roles: finished-LDS element becomes B (L2 phase)
        int   idxB  = idxA;
        float multB = multA;
        float4 xb0 = xa0, xb1 = xa1, xb2 = xa2, xb3 = xa3;
        const int elemB = wbase + (r - 1) * 4 + g;

        // issue next element's x loads NOW; pinned so they can't sink
        idxA = 0; multA = 1.0f;
        xr = reinterpret_cast<const float4*>(
            x + (size_t)(wbase + r * 4 + g) * NUM_INPUT);
        xa0 = xr[0 * 16 + s]; xa1 = xr[1 * 16 + s];
        xa2 = xr[2 * 16 + s]; xa3 = xr[3 * 16 + s];
        __builtin_amdgcn_sched_barrier(0);

        // B depths 6,7 (L2) — also cover xa load latency
        DEPTH_STEP(W, idxB, multB, xb0, xb1, xb2, xb3);
        DEPTH_STEP(W, idxB, multB, xb0, xb1, xb2, xb3);
        // interleave: A LDS-depths with B's remaining L2-depths
        DEPTH_STEP(lds_w, idxA, multA, xa0, xa1, xa2, xa3);   // A d0
        DEPTH_STEP(W,     idxB, multB, xb0, xb1, xb2, xb3);   // B d8
        DEPTH_STEP(lds_w, idxA, multA, xa0, xa1, xa2, xa3);   // A d1
        DEPTH_STEP(W,     idxB, multB, xb0, xb1, xb2, xb3);   // B d9
        DEPTH_STEP(lds_w, idxA, multA, xa0, xa1, xa2, xa3);   // A d2
        DEPTH_STEP(lds_w, idxA, multA, xa0, xa1, xa2, xa3);   // A d3
        DEPTH_STEP(lds_w, idxA, multA, xa0, xa1, xa2, xa3);   // A d4
        DEPTH_STEP(lds_w, idxA, multA, xa0, xa1, xa2, xa3);   // A d5

        STORE_OUT(elemB, idxB, multB);
    }

    // ---- drain: last element's L2 depths 6..9 ----
    #pragma unroll
    for (int d = STAGED_DEPTH; d < MAX_DEPTH; ++d)
        DEPTH_STEP(W, idxA, multA, xa0, xa1, xa2, xa3);
    STORE_OUT(wbase + (ROUNDS - 1) * 4 + g, idxA, multA);
}

extern "C" void kernel_launch(void* const* d_in, const int* in_sizes, int n_in,
                              void* d_out, int out_size, void* d_ws, size_t ws_size,
                              hipStream_t stream) {
    const float* x      = (const float*)d_in[0];
    const float* W      = (const float*)d_in[1];
    const float* b      = (const float*)d_in[2];
    const float* alpha  = (const float*)d_in[3];
    const float* leaves = (const float*)d_in[4];
    float* out = (float*)d_out;

    ogtree_kernel<<<BLOCKS, THREADS, 0, stream>>>(x, W, b, alpha, leaves, out);
}

// Round 7
// 50.222 us; speedup vs baseline: 1.2454x; 1.1615x over previous
//
#include <hip/hip_runtime.h>

#define NUM_INPUT   256
#define NUM_OUTPUT  64
#define MAX_DEPTH   10
#define N_INTERNAL  1023
#define STAGED_NODES 63          // tree levels 0..5 staged in LDS
#define STAGED_DEPTH 6
#define ELEMS_PER_WAVE 4         // 16 lanes per element
#define WAVES_PER_BLOCK 16
#define THREADS (WAVES_PER_BLOCK * 64)          // 1024
#define ELEMS_PER_BLOCK (WAVES_PER_BLOCK * ELEMS_PER_WAVE)  // 64

// Sum-reduce across each 16-lane row using DPP row_ror (VALU pipe, no DS ops).
__device__ __forceinline__ float group16_reduce_add(float acc) {
    int t;
    t = __builtin_amdgcn_update_dpp(0, __float_as_int(acc), 0x121, 0xf, 0xf, true); // row_ror:1
    acc += __int_as_float(t);
    t = __builtin_amdgcn_update_dpp(0, __float_as_int(acc), 0x122, 0xf, 0xf, true); // row_ror:2
    acc += __int_as_float(t);
    t = __builtin_amdgcn_update_dpp(0, __float_as_int(acc), 0x124, 0xf, 0xf, true); // row_ror:4
    acc += __int_as_float(t);
    t = __builtin_amdgcn_update_dpp(0, __float_as_int(acc), 0x128, 0xf, 0xf, true); // row_ror:8
    acc += __int_as_float(t);
    return acc;
}

// Product-reduce across each 16-lane row (same rotation pattern, multiply).
__device__ __forceinline__ float group16_reduce_mul(float v) {
    int t;
    t = __builtin_amdgcn_update_dpp(0, __float_as_int(v), 0x121, 0xf, 0xf, true);
    v *= __int_as_float(t);
    t = __builtin_amdgcn_update_dpp(0, __float_as_int(v), 0x122, 0xf, 0xf, true);
    v *= __int_as_float(t);
    t = __builtin_amdgcn_update_dpp(0, __float_as_int(v), 0x124, 0xf, 0xf, true);
    v *= __int_as_float(t);
    t = __builtin_amdgcn_update_dpp(0, __float_as_int(v), 0x128, 0xf, 0xf, true);
    v *= __int_as_float(t);
    return v;
}

__global__ __launch_bounds__(THREADS) void ogtree_kernel(
    const float* __restrict__ x,
    const float* __restrict__ W,
    const float* __restrict__ b,
    const float* __restrict__ alpha,
    const float* __restrict__ leaves,
    float* __restrict__ out)
{
    __shared__ float lds_w[STAGED_NODES * NUM_INPUT];  // 63 KB
    __shared__ float lds_b[N_INTERNAL];                // 4 KB
    __shared__ float lds_a[N_INTERNAL];                // 4 KB

    const int tid = threadIdx.x;

    // ---- stage W levels 0..5 (contiguous rows 0..62) + all b/alpha ----
    {
        const float4* Wv = reinterpret_cast<const float4*>(W);
        float4* lw4 = reinterpret_cast<float4*>(lds_w);
        #pragma unroll
        for (int i = tid; i < STAGED_NODES * NUM_INPUT / 4; i += THREADS)
            lw4[i] = Wv[i];
        for (int i = tid; i < N_INTERNAL; i += THREADS) {
            lds_b[i] = b[i];
            lds_a[i] = alpha[i];
        }
    }
    __syncthreads();

    const int lane = tid & 63;
    const int wid  = tid >> 6;
    const int g    = lane >> 4;   // element slot within wave (0..3)
    const int s    = lane & 15;   // sub-lane within element group
    const int elem = blockIdx.x * ELEMS_PER_BLOCK + wid * ELEMS_PER_WAVE + g;

    // ---- x fragment: 16 floats per lane, coalesced 256B per 16-lane group ----
    const float4* xrow = reinterpret_cast<const float4*>(x + (size_t)elem * NUM_INPUT);
    float4 xv0 = xrow[0 * 16 + s];
    float4 xv1 = xrow[1 * 16 + s];
    float4 xv2 = xrow[2 * 16 + s];
    float4 xv3 = xrow[3 * 16 + s];

    int   idx = 0;
    float zn[MAX_DEPTH];   // -|z_d| per depth; fully unrolled -> registers

    // One depth step: decision via z>=0 (== sigmoid(z)>=0.5); sigmoid itself is
    // DEFERRED — we only record -|z| (sign-bit OR). No trans ops in the loop.
    #define DEPTH_STEP(BASE, D)                                            \
    {                                                                      \
        const float4* wrow = reinterpret_cast<const float4*>(              \
            (BASE) + (size_t)idx * NUM_INPUT);                             \
        float a_i = lds_a[idx];                                            \
        float b_i = lds_b[idx];                                            \
        float4 w0 = wrow[0 * 16 + s];                                      \
        float4 w1 = wrow[1 * 16 + s];                                      \
        float4 w2 = wrow[2 * 16 + s];                                      \
        float4 w3 = wrow[3 * 16 + s];                                      \
        float acc0 = xv0.x * w0.x, acc1 = xv1.x * w1.x;                    \
        float acc2 = xv2.x * w2.x, acc3 = xv3.x * w3.x;                    \
        acc0 = fmaf(xv0.y, w0.y, acc0); acc1 = fmaf(xv1.y, w1.y, acc1);    \
        acc2 = fmaf(xv2.y, w2.y, acc2); acc3 = fmaf(xv3.y, w3.y, acc3);    \
        acc0 = fmaf(xv0.z, w0.z, acc0); acc1 = fmaf(xv1.z, w1.z, acc1);    \
        acc2 = fmaf(xv2.z, w2.z, acc2); acc3 = fmaf(xv3.z, w3.z, acc3);    \
        acc0 = fmaf(xv0.w, w0.w, acc0); acc1 = fmaf(xv1.w, w1.w, acc1);    \
        acc2 = fmaf(xv2.w, w2.w, acc2); acc3 = fmaf(xv3.w, w3.w, acc3);    \
        float acc = (acc0 + acc1) + (acc2 + acc3);                         \
        acc = group16_reduce_add(acc);                                     \
        float z = a_i * (acc + b_i);                                       \
        zn[D] = __int_as_float(__float_as_int(z) | 0x80000000);  /* -|z| */\
        bool right = (z >= 0.0f);                                          \
        idx = 2 * idx + 1 + (right ? 1 : 0);                               \
    }

    // depths 0..5: W from LDS
    #pragma unroll
    for (int d = 0; d < STAGED_DEPTH; ++d)
        DEPTH_STEP(lds_w, d);
    // depths 6..9: W gathered from global (L2-resident, 1 MB)
    #pragma unroll
    for (int d = STAGED_DEPTH; d < MAX_DEPTH; ++d)
        DEPTH_STEP(W, d);
    #undef DEPTH_STEP

    // ---- deferred sigmoid epilogue (lane-parallel across the 16-lane group):
    // mult = prod_d sigmoid(|z_d|) = 1 / prod_d (1 + exp(-|z_d|)).
    // Lane d handles depth d; lanes 10..15 contribute factor 1 (exp(-1e30)=0).
    float zsel = -1e30f;
    #pragma unroll
    for (int d = 0; d < MAX_DEPTH; ++d)
        zsel = (s == d) ? zn[d] : zsel;
    float f = 1.0f + __expf(zsel);          // one trans op per element
    float p = group16_reduce_mul(f);        // prod over the 16-lane row
    float mult = 1.0f / p;

    // ---- out[elem] = mult * leaves[idx - 1023] ----
    const int leaf = idx - N_INTERNAL;
    const float4 lv = reinterpret_cast<const float4*>(
        leaves + (size_t)leaf * NUM_OUTPUT)[s];
    float4 o;
    o.x = mult * lv.x;
    o.y = mult * lv.y;
    o.z = mult * lv.z;
    o.w = mult * lv.w;
    reinterpret_cast<float4*>(out + (size_t)elem * NUM_OUTPUT)[s] = o;
}

extern "C" void kernel_launch(void* const* d_in, const int* in_sizes, int n_in,
                              void* d_out, int out_size, void* d_ws, size_t ws_size,
                              hipStream_t stream) {
    const float* x      = (const float*)d_in[0];
    const float* W      = (const float*)d_in[1];
    const float* b      = (const float*)d_in[2];
    const float* alpha  = (const float*)d_in[3];
    const float* leaves = (const float*)d_in[4];
    float* out = (float*)d_out;

    const int batch  = in_sizes[0] / NUM_INPUT;           // 131072
    const int blocks = batch / ELEMS_PER_BLOCK;           // 2048

    ogtree_kernel<<<blocks, THREADS, 0, stream>>>(x, W, b, alpha, leaves, out);
}

// Round 8
// 49.425 us; speedup vs baseline: 1.2655x; 1.0161x over previous
//
#include <hip/hip_runtime.h>

#define NUM_INPUT   256
#define NUM_OUTPUT  64
#define MAX_DEPTH   10
#define N_INTERNAL  1023
#define STAGED_NODES 31          // tree levels 0..4 staged in LDS (31 KB)
#define STAGED_DEPTH 5
#define ELEMS_PER_WAVE 4         // 16 lanes per element
#define WAVES_PER_BLOCK 8
#define THREADS (WAVES_PER_BLOCK * 64)          // 512 -> 4 blocks/CU
#define ELEMS_PER_BLOCK (WAVES_PER_BLOCK * ELEMS_PER_WAVE)  // 32

// Sum-reduce across each 16-lane row using DPP row_ror (VALU pipe, no DS ops).
__device__ __forceinline__ float group16_reduce_add(float acc) {
    int t;
    t = __builtin_amdgcn_update_dpp(0, __float_as_int(acc), 0x121, 0xf, 0xf, true); // row_ror:1
    acc += __int_as_float(t);
    t = __builtin_amdgcn_update_dpp(0, __float_as_int(acc), 0x122, 0xf, 0xf, true); // row_ror:2
    acc += __int_as_float(t);
    t = __builtin_amdgcn_update_dpp(0, __float_as_int(acc), 0x124, 0xf, 0xf, true); // row_ror:4
    acc += __int_as_float(t);
    t = __builtin_amdgcn_update_dpp(0, __float_as_int(acc), 0x128, 0xf, 0xf, true); // row_ror:8
    acc += __int_as_float(t);
    return acc;
}

// Product-reduce across each 16-lane row (same rotation pattern, multiply).
__device__ __forceinline__ float group16_reduce_mul(float v) {
    int t;
    t = __builtin_amdgcn_update_dpp(0, __float_as_int(v), 0x121, 0xf, 0xf, true);
    v *= __int_as_float(t);
    t = __builtin_amdgcn_update_dpp(0, __float_as_int(v), 0x122, 0xf, 0xf, true);
    v *= __int_as_float(t);
    t = __builtin_amdgcn_update_dpp(0, __float_as_int(v), 0x124, 0xf, 0xf, true);
    v *= __int_as_float(t);
    t = __builtin_amdgcn_update_dpp(0, __float_as_int(v), 0x128, 0xf, 0xf, true);
    v *= __int_as_float(t);
    return v;
}

__global__ __launch_bounds__(THREADS, 8) void ogtree_kernel(
    const float* __restrict__ x,
    const float* __restrict__ W,
    const float* __restrict__ b,
    const float* __restrict__ alpha,
    const float* __restrict__ leaves,
    float* __restrict__ out)
{
    __shared__ float lds_w[STAGED_NODES * NUM_INPUT];  // 31 KB
    __shared__ float lds_b[N_INTERNAL];                // 4 KB
    __shared__ float lds_a[N_INTERNAL];                // 4 KB

    const int tid  = threadIdx.x;
    const int lane = tid & 63;
    const int wid  = tid >> 6;
    const int g    = lane >> 4;   // element slot within wave (0..3)
    const int s    = lane & 15;   // sub-lane within element group
    const int elem = blockIdx.x * ELEMS_PER_BLOCK + wid * ELEMS_PER_WAVE + g;

    // ---- x loads issued BEFORE staging: L3 latency hides under the stage ----
    const float4* xrow = reinterpret_cast<const float4*>(x + (size_t)elem * NUM_INPUT);
    float4 xv0 = xrow[0 * 16 + s];
    float4 xv1 = xrow[1 * 16 + s];
    float4 xv2 = xrow[2 * 16 + s];
    float4 xv3 = xrow[3 * 16 + s];

    // ---- stage W levels 0..4 (rows 0..30) + all b/alpha ----
    {
        const float4* Wv = reinterpret_cast<const float4*>(W);
        float4* lw4 = reinterpret_cast<float4*>(lds_w);
        #pragma unroll
        for (int i = tid; i < STAGED_NODES * NUM_INPUT / 4; i += THREADS)
            lw4[i] = Wv[i];
        for (int i = tid; i < N_INTERNAL; i += THREADS) {
            lds_b[i] = b[i];
            lds_a[i] = alpha[i];
        }
    }
    __syncthreads();

    int   idx = 0;
    float zn[MAX_DEPTH];   // -|z_d| per depth; fully unrolled -> registers

    // One depth step: decision via z>=0 (== sigmoid(z)>=0.5); sigmoid DEFERRED.
    #define DEPTH_STEP(BASE, D)                                            \
    {                                                                      \
        const float4* wrow = reinterpret_cast<const float4*>(              \
            (BASE) + (size_t)idx * NUM_INPUT);                             \
        float a_i = lds_a[idx];                                            \
        float b_i = lds_b[idx];                                            \
        float4 w0 = wrow[0 * 16 + s];                                      \
        float4 w1 = wrow[1 * 16 + s];                                      \
        float4 w2 = wrow[2 * 16 + s];                                      \
        float4 w3 = wrow[3 * 16 + s];                                      \
        float acc0 = xv0.x * w0.x, acc1 = xv1.x * w1.x;                    \
        float acc2 = xv2.x * w2.x, acc3 = xv3.x * w3.x;                    \
        acc0 = fmaf(xv0.y, w0.y, acc0); acc1 = fmaf(xv1.y, w1.y, acc1);    \
        acc2 = fmaf(xv2.y, w2.y, acc2); acc3 = fmaf(xv3.y, w3.y, acc3);    \
        acc0 = fmaf(xv0.z, w0.z, acc0); acc1 = fmaf(xv1.z, w1.z, acc1);    \
        acc2 = fmaf(xv2.z, w2.z, acc2); acc3 = fmaf(xv3.z, w3.z, acc3);    \
        acc0 = fmaf(xv0.w, w0.w, acc0); acc1 = fmaf(xv1.w, w1.w, acc1);    \
        acc2 = fmaf(xv2.w, w2.w, acc2); acc3 = fmaf(xv3.w, w3.w, acc3);    \
        float acc = (acc0 + acc1) + (acc2 + acc3);                         \
        acc = group16_reduce_add(acc);                                     \
        float z = a_i * (acc + b_i);                                       \
        zn[D] = __int_as_float(__float_as_int(z) | 0x80000000);  /* -|z| */\
        bool right = (z >= 0.0f);                                          \
        idx = 2 * idx + 1 + (right ? 1 : 0);                               \
    }

    // depths 0..4: W from LDS
    #pragma unroll
    for (int d = 0; d < STAGED_DEPTH; ++d)
        DEPTH_STEP(lds_w, d);
    // depths 5..9: W gathered from global (hot in L2)
    #pragma unroll
    for (int d = STAGED_DEPTH; d < MAX_DEPTH; ++d)
        DEPTH_STEP(W, d);
    #undef DEPTH_STEP

    // ---- deferred sigmoid epilogue (lane-parallel across the 16-lane group):
    // mult = prod_d sigmoid(|z_d|) = 1 / prod_d (1 + exp(-|z_d|)).
    float zsel = -1e30f;
    #pragma unroll
    for (int d = 0; d < MAX_DEPTH; ++d)
        zsel = (s == d) ? zn[d] : zsel;
    float f = 1.0f + __expf(zsel);          // one trans op per element
    float p = group16_reduce_mul(f);        // prod over the 16-lane row
    float mult = 1.0f / p;

    // ---- out[elem] = mult * leaves[idx - 1023] ----
    const int leaf = idx - N_INTERNAL;
    const float4 lv = reinterpret_cast<const float4*>(
        leaves + (size_t)leaf * NUM_OUTPUT)[s];
    float4 o;
    o.x = mult * lv.x;
    o.y = mult * lv.y;
    o.z = mult * lv.z;
    o.w = mult * lv.w;
    reinterpret_cast<float4*>(out + (size_t)elem * NUM_OUTPUT)[s] = o;
}

extern "C" void kernel_launch(void* const* d_in, const int* in_sizes, int n_in,
                              void* d_out, int out_size, void* d_ws, size_t ws_size,
                              hipStream_t stream) {
    const float* x      = (const float*)d_in[0];
    const float* W      = (const float*)d_in[1];
    const float* b      = (const float*)d_in[2];
    const float* alpha  = (const float*)d_in[3];
    const float* leaves = (const float*)d_in[4];
    float* out = (float*)d_out;

    const int batch  = in_sizes[0] / NUM_INPUT;           // 131072
    const int blocks = batch / ELEMS_PER_BLOCK;           // 4096

    ogtree_kernel<<<blocks, THREADS, 0, stream>>>(x, W, b, alpha, leaves, out);
}